// Round 10
// baseline (321.856 us; speedup 1.0000x reference)
//
#include <hip/hip_runtime.h>
#include <hip/hip_bf16.h>
#include <cstddef>

#define EE 1024            // E
#define MTOT 8192          // B*E

using floatx4 = __attribute__((ext_vector_type(4))) float;
using bf16x8  = __attribute__((ext_vector_type(8))) __bf16;

union FragU { uint4 u; bf16x8 b; };

__device__ __forceinline__ float elu1(float x) {
    return x > 0.f ? x + 1.f : __expf(x);
}

__device__ __forceinline__ unsigned int pack2bf(float x, float y) {
    __hip_bfloat162 h = __float22bfloat162_rn(make_float2(x, y));
    union { __hip_bfloat162 h; unsigned int u; } c;
    c.h = h;
    return c.u;
}

__device__ __forceinline__ uint4 pack8bf(const float4 a, const float4 b) {
    uint4 r;
    r.x = pack2bf(a.x, a.y); r.y = pack2bf(a.z, a.w);
    r.z = pack2bf(b.x, b.y); r.w = pack2bf(b.z, b.w);
    return r;
}

__device__ __forceinline__ unsigned short f2bf(float x) {
    union { __hip_bfloat16 h; unsigned short s; } c;
    c.h = __float2bfloat16(x);
    return c.s;
}

__device__ __forceinline__ void unp8(const uint4 p, float4& a, float4& b) {
    a.x = __uint_as_float(p.x << 16); a.y = __uint_as_float(p.x & 0xffff0000u);
    a.z = __uint_as_float(p.y << 16); a.w = __uint_as_float(p.y & 0xffff0000u);
    b.x = __uint_as_float(p.z << 16); b.y = __uint_as_float(p.z & 0xffff0000u);
    b.z = __uint_as_float(p.w << 16); b.w = __uint_as_float(p.w & 0xffff0000u);
}

__device__ __forceinline__ void ld_lds16(const unsigned short* g, unsigned short* l) {
    __builtin_amdgcn_global_load_lds(
        (const __attribute__((address_space(1))) void*)g,
        (__attribute__((address_space(3))) void*)l, 16, 0, 0);
}

// Fused fp32 -> bf16 bulk convert: x | Wq | Wk | Wv | Wo in one launch.
__global__ __launch_bounds__(256)
void cvt_all(const float* __restrict__ x,
             const float* __restrict__ Wq, const float* __restrict__ Wk,
             const float* __restrict__ Wv, const float* __restrict__ Wo,
             unsigned short* __restrict__ xb,
             unsigned short* __restrict__ wb, unsigned short* __restrict__ wob) {
    const int i = blockIdx.x * 256 + threadIdx.x;
    if (i >= 3014656) return;
    const float* src;
    unsigned short* dst;
    int off;
    if (i < 2097152)      { src = x;  dst = xb;           off = i; }
    else if (i < 2359296) { src = Wq; dst = wb;           off = i - 2097152; }
    else if (i < 2621440) { src = Wk; dst = wb + 2097152; off = i - 2359296; }
    else if (i < 2883584) { src = Wv; dst = wb + 4194304; off = i - 2621440; }
    else                  { src = Wo; dst = wob;          off = i - 2883584; }
    const float4 a = ((const float4*)src)[2 * off];
    const float4 b = ((const float4*)src)[2 * off + 1];
    ((uint4*)dst)[off] = pack8bf(a, b);
}

// ---- m97-style MFMA core, BK=64 (r7-proven: 868 TF, 0 bank conflicts).
template<int K>
__device__ __forceinline__ void mfma_core(const unsigned short* __restrict__ A,
                                          const unsigned short* __restrict__ B,
                                          int m0, int n0,
                                          unsigned short* As, unsigned short* Bs,
                                          floatx4 (&acc)[4][4]) {
    const int t = threadIdx.x;
    const int w = t >> 6, l = t & 63;
    const int wm = (w >> 1) * 64, wn = (w & 1) * 64;
    const int lm = l & 15, lq = l >> 4;
    const int lr = l >> 3;                       // row within 8-row stage group
    const int sc = ((l & 7) - lr) & 7;           // pre-swizzled source chunk
    const int c0 = (lq + lm) & 7;                // read-side base slot

    const unsigned short* Ag = A + (size_t)(m0 + 32 * w + lr) * K + sc * 8;
    const unsigned short* Bg = B + (size_t)(n0 + 32 * w + lr) * K + sc * 8;
    unsigned short* Al = As + (32 * w) * 64;
    unsigned short* Bl = Bs + (32 * w) * 64;

    for (int kb = 0; kb < K; kb += 64) {
        __syncthreads();
        #pragma unroll
        for (int p = 0; p < 4; ++p) {
            ld_lds16(Ag + (size_t)(8 * p) * K + kb, Al + (8 * p) * 64);
            ld_lds16(Bg + (size_t)(8 * p) * K + kb, Bl + (8 * p) * 64);
        }
        __syncthreads();
        FragU af[4][2], bf[4][2];
        #pragma unroll
        for (int i = 0; i < 4; ++i) {
            const int row = (wm + i * 16 + lm) * 64;
            af[i][0].u = *(const uint4*)&As[row + c0 * 8];
            af[i][1].u = *(const uint4*)&As[row + (c0 ^ 4) * 8];
        }
        #pragma unroll
        for (int j = 0; j < 4; ++j) {
            const int row = (wn + j * 16 + lm) * 64;
            bf[j][0].u = *(const uint4*)&Bs[row + c0 * 8];
            bf[j][1].u = *(const uint4*)&Bs[row + (c0 ^ 4) * 8];
        }
        #pragma unroll
        for (int i = 0; i < 4; ++i)
            #pragma unroll
            for (int j = 0; j < 4; ++j) {
                acc[i][j] = __builtin_amdgcn_mfma_f32_16x16x32_bf16(
                    af[i][0].b, bf[j][0].b, acc[i][j], 0, 0, 0);
                acc[i][j] = __builtin_amdgcn_mfma_f32_16x16x32_bf16(
                    af[i][1].b, bf[j][1].b, acc[i][j], 0, 0, 0);
            }
    }
}

// Fused QKV projection: A=xb [8192][2048], B=wb [3072][2048] (Wq|Wk|Wv rows).
__global__ __launch_bounds__(256)
void gemm_qkv(const unsigned short* __restrict__ A, const unsigned short* __restrict__ B,
              const float* __restrict__ bq, const float* __restrict__ bk,
              const float* __restrict__ bv,
              unsigned short* __restrict__ qb, unsigned short* __restrict__ kb,
              unsigned short* __restrict__ vb) {
    __shared__ __align__(16) unsigned short As[128 * 64];
    __shared__ __align__(16) unsigned short Bs[128 * 64];
    int id = blockIdx.y * 24 + blockIdx.x;
    id = (id & 7) * 192 + (id >> 3);
    const int m0 = (id / 24) * 128;
    const int n0 = (id % 24) * 128;
    floatx4 acc[4][4];
    #pragma unroll
    for (int i = 0; i < 4; ++i)
        #pragma unroll
        for (int j = 0; j < 4; ++j)
            acc[i][j] = (floatx4)(0.f);
    mfma_core<2048>(A, B, m0, n0, As, Bs, acc);

    const int t = threadIdx.x;
    const int w = t >> 6, l = t & 63;
    const int wm = (w >> 1) * 64, wn = (w & 1) * 64;
    const int lm = l & 15, lq = l >> 4;
    const int proj = n0 >> 10;
    unsigned short* Cb = proj == 0 ? qb : (proj == 1 ? kb : vb);
    const float* bias  = proj == 0 ? bq : (proj == 1 ? bk : bv);
    const int nd = n0 & 1023;
    #pragma unroll
    for (int j = 0; j < 4; ++j) {
        const int d = nd + wn + j * 16 + lm;
        const float bj = bias[d];
        #pragma unroll
        for (int i = 0; i < 4; ++i) {
            #pragma unroll
            for (int r = 0; r < 4; ++r) {
                const int row = m0 + wm + i * 16 + lq * 4 + r;
                Cb[(size_t)row * 1024 + d] = f2bf(acc[i][j][r] + bj);
            }
        }
    }
}

// Output projection: A=attn bf16 [8192][1024], B=wob [1024][1024]. fp32 out.
__global__ __launch_bounds__(256)
void gemm_out(const unsigned short* __restrict__ A, const unsigned short* __restrict__ B,
              const float* __restrict__ bo, float* __restrict__ C) {
    __shared__ __align__(16) unsigned short As[128 * 64];
    __shared__ __align__(16) unsigned short Bs[128 * 64];
    int id = blockIdx.y * 8 + blockIdx.x;
    id = (id & 7) * 64 + (id >> 3);
    const int m0 = (id / 8) * 128;
    const int n0 = (id % 8) * 128;
    floatx4 acc[4][4];
    #pragma unroll
    for (int i = 0; i < 4; ++i)
        #pragma unroll
        for (int j = 0; j < 4; ++j)
            acc[i][j] = (floatx4)(0.f);
    mfma_core<1024>(A, B, m0, n0, As, Bs, acc);

    const int t = threadIdx.x;
    const int w = t >> 6, l = t & 63;
    const int wm = (w >> 1) * 64, wn = (w & 1) * 64;
    const int lm = l & 15, lq = l >> 4;
    #pragma unroll
    for (int j = 0; j < 4; ++j) {
        const int col = n0 + wn + j * 16 + lm;
        const float bj = bo[col];
        #pragma unroll
        for (int i = 0; i < 4; ++i) {
            #pragma unroll
            for (int r = 0; r < 4; ++r) {
                const int row = m0 + wm + i * 16 + lq * 4 + r;
                C[(size_t)row * EE + col] = acc[i][j][r] + bj;
            }
        }
    }
}

// ---- Stage 1 (MFMA): Sk^T[e][d] = sum_s v[s][e]*sigma_k[s][d] (TRANSPOSED
// output vs before -- free: just swap the MFMA operand roles; coalescing of
// the C-write is identical). z[d]=colsum(sigma_k) unchanged.
// Sk^T layout [e][d] makes seg_attn's mem^T staging a pure vector copy.
__global__ __launch_bounds__(256)
void seg_kv(const unsigned short* __restrict__ k, const unsigned short* __restrict__ v,
            float* __restrict__ Skv, float* __restrict__ zc) {
    __shared__ __align__(16) unsigned short KT[64 * 72];  // sigma_k^T [d][s]
    __shared__ __align__(16) unsigned short VT[64 * 72];  // v^T       [e][s]
    const int t = threadIdx.x;
    const int w = t >> 6, l = t & 63, quad = l >> 4, lm = l & 15;
    const size_t base = (size_t)blockIdx.x * 4096;

    #pragma unroll
    for (int i = 0; i < 2; ++i) {
        const int c  = t + i * 256;            // uint4 chunk
        const int sr = c >> 3, c0 = (c & 7) * 8;
        const uint4 pk = *(const uint4*)(k + base + c * 8);
        const uint4 pv = *(const uint4*)(v + base + c * 8);
        float4 f0, f1;
        unp8(pk, f0, f1);
        KT[(c0 + 0) * 72 + sr] = f2bf(elu1(f0.x));
        KT[(c0 + 1) * 72 + sr] = f2bf(elu1(f0.y));
        KT[(c0 + 2) * 72 + sr] = f2bf(elu1(f0.z));
        KT[(c0 + 3) * 72 + sr] = f2bf(elu1(f0.w));
        KT[(c0 + 4) * 72 + sr] = f2bf(elu1(f1.x));
        KT[(c0 + 5) * 72 + sr] = f2bf(elu1(f1.y));
        KT[(c0 + 6) * 72 + sr] = f2bf(elu1(f1.z));
        KT[(c0 + 7) * 72 + sr] = f2bf(elu1(f1.w));
        const unsigned short* pvs = (const unsigned short*)&pv;
        #pragma unroll
        for (int jj = 0; jj < 8; ++jj) VT[(c0 + jj) * 72 + sr] = pvs[jj];
    }
    __syncthreads();

    if (t < 64) {                                  // z[d] = rowsum of KT row d
        float ssum = 0.f;
        #pragma unroll
        for (int c2 = 0; c2 < 8; ++c2) {
            const uint4 p = *(const uint4*)&KT[t * 72 + c2 * 8];
            float4 a, b;
            unp8(p, a, b);
            ssum += a.x + a.y + a.z + a.w + b.x + b.y + b.z + b.w;
        }
        zc[(size_t)blockIdx.x * 64 + t] = ssum;
    }

    // A-frag from VT (rows = e), B-frag from KT (rows = d) -> D[e][d] = Sk^T
    FragU av0, av1;
    av0.u = *(const uint4*)&VT[(16 * w + lm) * 72 + quad * 8];
    av1.u = *(const uint4*)&VT[(16 * w + lm) * 72 + 32 + quad * 8];
    floatx4 C4[4];
    #pragma unroll
    for (int j = 0; j < 4; ++j) C4[j] = (floatx4)(0.f);
    #pragma unroll
    for (int j = 0; j < 4; ++j) {
        FragU b0, b1;
        b0.u = *(const uint4*)&KT[(j * 16 + lm) * 72 + quad * 8];
        b1.u = *(const uint4*)&KT[(j * 16 + lm) * 72 + 32 + quad * 8];
        C4[j] = __builtin_amdgcn_mfma_f32_16x16x32_bf16(av0.b, b0.b, C4[j], 0, 0, 0);
        C4[j] = __builtin_amdgcn_mfma_f32_16x16x32_bf16(av1.b, b1.b, C4[j], 0, 0, 0);
    }
    const int e0 = 16 * w + quad * 4;
    #pragma unroll
    for (int j = 0; j < 4; ++j)
        #pragma unroll
        for (int r = 0; r < 4; ++r)
            Skv[base + (size_t)(e0 + r) * 64 + j * 16 + lm] = C4[j][r];
}

// ---- Stage 2: exclusive prefix over 16 segments per (b,h) chain.
// Elementwise over [e][d] layout (layout-agnostic). fp32 accum, bf16 out.
__global__ __launch_bounds__(256)
void prefix_mem(const float* __restrict__ Skv, unsigned short* __restrict__ Skvb,
                float* __restrict__ zc) {
    const int t  = threadIdx.x;
    const int bh = blockIdx.y;
    const size_t off = (size_t)bh * 16 * 4096 + blockIdx.x * 512 + t * 2;
    float2 acc = make_float2(0.f, 0.f);
    #pragma unroll
    for (int n = 0; n < 16; ++n) {
        const float2 tmp = *(const float2*)(Skv + off + (size_t)n * 4096);
        *(unsigned int*)(Skvb + off + (size_t)n * 4096) = pack2bf(acc.x, acc.y);
        acc.x += tmp.x; acc.y += tmp.y;
    }
    if (blockIdx.x == 0 && t < 64) {
        float* zp0 = zc + (size_t)bh * 16 * 64 + t;
        float za = 0.f;
        #pragma unroll
        for (int n = 0; n < 16; ++n) {
            float* zp = zp0 + n * 64;
            const float tmp = *zp;
            *zp = za;
            za += tmp;
        }
    }
}

// ---- Stage 3 (MFMA): per-segment attention. mem bf16 in Sk^T layout [e][d]
// -> MT staging is a pure vector copy. rs derived from sigma_q frags (one elu
// pass total). Softmax without max-subtraction (|scores| <= |q||k|/8 ~ 6.5 by
// Cauchy-Schwarz -> no overflow; mathematically identical).
__global__ __launch_bounds__(256)
void seg_attn(const unsigned short* __restrict__ q, const unsigned short* __restrict__ k,
              const unsigned short* __restrict__ v, const unsigned short* __restrict__ memb,
              const float* __restrict__ zp, const float* __restrict__ beta,
              unsigned short* __restrict__ ab) {
    __shared__ __align__(16) unsigned short Pb[64 * 72];  // P bf16 [s][t]
    __shared__ __align__(16) unsigned short VT[64 * 72];  // v^T    [e][s]
    __shared__ __align__(16) unsigned short MT[64 * 72];  // mem^T  [e][d]
    __shared__ float rs[64];
    __shared__ float zr[64];
    const int t = threadIdx.x;
    const int w = t >> 6, l = t & 63, quad = l >> 4, lm = l & 15;
    const int seg = blockIdx.x;
    const int h   = (seg >> 4) & 15;
    const float gate = 1.f / (1.f + __expf(-10.f * beta[h]));
    const float omg  = 1.f - gate;
    const size_t base = (size_t)seg * 4096;

    // stage v^T (transpose: contraction for P@V is over stored row index)
    #pragma unroll
    for (int i = 0; i < 2; ++i) {
        const int c  = t + i * 256;
        const int sr = c >> 3, c0 = (c & 7) * 8;
        const uint4 pv = *(const uint4*)(v + base + c * 8);
        const unsigned short* pvs = (const unsigned short*)&pv;
        #pragma unroll
        for (int jj = 0; jj < 8; ++jj) VT[(c0 + jj) * 72 + sr] = pvs[jj];
    }
    // stage mem^T: memb is ALREADY [e][d] -> straight vector copy
    #pragma unroll
    for (int i = 0; i < 2; ++i) {
        const int c = t + i * 256;
        const int e = c >> 3, d0 = (c & 7) * 8;
        *(uint4*)&MT[e * 72 + d0] = *(const uint4*)(memb + base + c * 8);
    }
    if (t < 64) zr[t] = zp[(size_t)seg * 64 + t];
    __syncthreads();

    // ---- per-wave: q frags, sigma_q frags + rs (single elu pass)
    const unsigned short* qrow = q + base + (size_t)(16 * w + lm) * 64;
    FragU aq0, aq1, as0, as1;
    aq0.u = *(const uint4*)(qrow + quad * 8);
    aq1.u = *(const uint4*)(qrow + 32 + quad * 8);
    {
        float4 f0, f1, f2, f3;
        unp8(aq0.u, f0, f1);
        unp8(aq1.u, f2, f3);
        f0.x = elu1(f0.x); f0.y = elu1(f0.y); f0.z = elu1(f0.z); f0.w = elu1(f0.w);
        f1.x = elu1(f1.x); f1.y = elu1(f1.y); f1.z = elu1(f1.z); f1.w = elu1(f1.w);
        f2.x = elu1(f2.x); f2.y = elu1(f2.y); f2.z = elu1(f2.z); f2.w = elu1(f2.w);
        f3.x = elu1(f3.x); f3.y = elu1(f3.y); f3.z = elu1(f3.z); f3.w = elu1(f3.w);
        float part = f0.x + f0.y + f0.z + f0.w + f1.x + f1.y + f1.z + f1.w
                   + f2.x + f2.y + f2.z + f2.w + f3.x + f3.y + f3.z + f3.w;
        part += __shfl_xor(part, 16, 64);
        part += __shfl_xor(part, 32, 64);
        if (quad == 0) rs[16 * w + lm] = part;    // same-wave consumer only
        as0.u = pack8bf(f0, f1);
        as1.u = pack8bf(f2, f3);
    }

    // ---- scores: wave w computes rows [16w,16w+16) x all 64 cols
    floatx4 S[4];
    #pragma unroll
    for (int j = 0; j < 4; ++j) S[j] = (floatx4)(0.f);
    #pragma unroll
    for (int j = 0; j < 4; ++j) {
        const unsigned short* krow = k + base + (size_t)(j * 16 + lm) * 64;
        FragU b0, b1;
        b0.u = *(const uint4*)(krow + quad * 8);
        b1.u = *(const uint4*)(krow + 32 + quad * 8);
        S[j] = __builtin_amdgcn_mfma_f32_16x16x32_bf16(aq0.b, b0.b, S[j], 0, 0, 0);
        S[j] = __builtin_amdgcn_mfma_f32_16x16x32_bf16(aq1.b, b1.b, S[j], 0, 0, 0);
    }
    // ---- causal softmax (no max-sub; exact same math); write P bf16 to LDS
    const int srow0 = 16 * w + quad * 4;
    #pragma unroll
    for (int r = 0; r < 4; ++r) {
        const int s_g = srow0 + r;
        float ss = 0.f;
        #pragma unroll
        for (int j = 0; j < 4; ++j) {
            const int t_g = j * 16 + lm;
            const float e = (t_g <= s_g) ? __expf(S[j][r] * 0.125f) : 0.f;
            S[j][r] = e;
            ss += e;
        }
        ss += __shfl_xor(ss, 1, 64);
        ss += __shfl_xor(ss, 2, 64);
        ss += __shfl_xor(ss, 4, 64);
        ss += __shfl_xor(ss, 8, 64);
        const float inv = 1.f / ss;
        #pragma unroll
        for (int j = 0; j < 4; ++j)
            Pb[s_g * 72 + j * 16 + lm] = f2bf(S[j][r] * inv);
    }
    __syncthreads();

    // ---- A_dot = P@V and A_mem = sigma_q@mem (both C-layout accumulators)
    FragU ap0, ap1;
    ap0.u = *(const uint4*)&Pb[(16 * w + lm) * 72 + quad * 8];
    ap1.u = *(const uint4*)&Pb[(16 * w + lm) * 72 + 32 + quad * 8];
    floatx4 AD[4], AM[4];
    #pragma unroll
    for (int j = 0; j < 4; ++j) { AD[j] = (floatx4)(0.f); AM[j] = (floatx4)(0.f); }
    #pragma unroll
    for (int j = 0; j < 4; ++j) {
        FragU bv0, bv1, bm0, bm1;
        bv0.u = *(const uint4*)&VT[(j * 16 + lm) * 72 + quad * 8];
        bv1.u = *(const uint4*)&VT[(j * 16 + lm) * 72 + 32 + quad * 8];
        bm0.u = *(const uint4*)&MT[(j * 16 + lm) * 72 + quad * 8];
        bm1.u = *(const uint4*)&MT[(j * 16 + lm) * 72 + 32 + quad * 8];
        AD[j] = __builtin_amdgcn_mfma_f32_16x16x32_bf16(ap0.b, bv0.b, AD[j], 0, 0, 0);
        AD[j] = __builtin_amdgcn_mfma_f32_16x16x32_bf16(ap1.b, bv1.b, AD[j], 0, 0, 0);
        AM[j] = __builtin_amdgcn_mfma_f32_16x16x32_bf16(as0.b, bm0.b, AM[j], 0, 0, 0);
        AM[j] = __builtin_amdgcn_mfma_f32_16x16x32_bf16(as1.b, bm1.b, AM[j], 0, 0, 0);
    }
    // ---- combine + store attn bf16
    #pragma unroll
    for (int j = 0; j < 4; ++j) {
        const int d = j * 16 + lm;
        const float zd = zr[d];
        #pragma unroll
        for (int r = 0; r < 4; ++r) {
            const int s_g = srow0 + r;
            const float den = rs[s_g] * zd + 1e-6f;
            const float o = gate * (AM[j][r] / den) + omg * AD[j][r];
            ab[base + (size_t)s_g * 64 + d] = f2bf(o);
        }
    }
}

extern "C" void kernel_launch(void* const* d_in, const int* in_sizes, int n_in,
                              void* d_out, int out_size, void* d_ws, size_t ws_size,
                              hipStream_t stream) {
    const float* x    = (const float*)d_in[0];
    const float* Wq   = (const float*)d_in[1];
    const float* bq   = (const float*)d_in[2];
    const float* Wk   = (const float*)d_in[3];
    const float* bk   = (const float*)d_in[4];
    const float* Wv   = (const float*)d_in[5];
    const float* bv   = (const float*)d_in[6];
    const float* Wo   = (const float*)d_in[7];
    const float* bo   = (const float*)d_in[8];
    const float* beta = (const float*)d_in[9];
    float* out = (float*)d_out;

    unsigned char* wsb = (unsigned char*)d_ws;
    unsigned short* xb  = (unsigned short*)(wsb);                       // 32 MB
    unsigned short* wb  = (unsigned short*)(wsb + (32ull << 20));       // 12 MB  [3072][2048]
    unsigned short* wob = (unsigned short*)(wsb + (44ull << 20));       // 2 MB   [1024][1024]
    unsigned short* qb  = (unsigned short*)(wsb + (46ull << 20));       // 16 MB
    unsigned short* kb  = (unsigned short*)(wsb + (62ull << 20));       // 16 MB
    unsigned short* vb  = (unsigned short*)(wsb + (78ull << 20));       // 16 MB
    float* Skv = (float*)(wsb + (94ull << 20));                         // 32 MB
    float* zc  = (float*)(wsb + (126ull << 20));                        // 0.5 MB
    unsigned short* ab   = xb;                                          // first 16 MB of xb (dead after gemm_qkv)
    unsigned short* Skvb = (unsigned short*)(wsb + (16ull << 20));      // second 16 MB of xb (dead after gemm_qkv)

    cvt_all<<<11776, 256, 0, stream>>>(x, Wq, Wk, Wv, Wo, xb, wb, wob);

    gemm_qkv<<<dim3(24, 64), 256, 0, stream>>>(xb, wb, bq, bk, bv, qb, kb, vb);
    seg_kv<<<2048, 256, 0, stream>>>(kb, vb, Skv, zc);
    prefix_mem<<<dim3(8, 128), 256, 0, stream>>>(Skv, Skvb, zc);
    seg_attn<<<2048, 256, 0, stream>>>(qb, kb, vb, Skvb, zc, beta, ab);
    gemm_out<<<dim3(8, 64), 256, 0, stream>>>(ab, wob, bo, out);
}